// Round 12
// baseline (103023.901 us; speedup 1.0000x reference)
//
#include <hip/hip_runtime.h>
#include <math.h>

// R12 = R11 with the MLP re-tiled CELL-SPLIT (bit-exact):
//   16 waves = 8 u-groups (10u) x 2 cell-halves (64 cells), lane owns 1 cell.
//   Each wave reads only its half of hbuf, with scalar b32 reads ->
//   LDS read traffic halved (1.3MB -> 0.65MB per step per block).
//   L4 partials stored as TWO 5-u partials per wave so the corr sum runs
//   over the identical 16 partials in the identical order as R9/R11.
//   Weights repacked to the R7-proven 8-group x [20kb][4kp][12] layout.
// Plus: kk-phase sequential Sv uses float4 row loads (same m-ascending FMA
// chain -> same bits, 4x fewer LDS instructions in the norm epoch).

#define NB 32
#define NN 32
#define NSTEPS 600
#define NT1 601
#define NSI 10
#define NH 75
#define NU 80      // padded u
#define NKB 20     // padded k-blocks of 4 (k padded 75 -> 80)
#define NIB 8      // sibling blocks per batch element (grid = 256 = #CUs)

#define ICM2IFS 2.99792458e-05
#define KBOLTZ 0.6950389f
#define TWO_PI 6.283185307179586476925286766559

__device__ __forceinline__ float elu1(float x) { return x > 0.f ? x : (__expf(x) - 1.f); }

// ---------------------------------------------------------------------------
// Phase A: batched 32x32 symmetric eigensolver (parallel cyclic Jacobi).
// R9-proven version: 128 threads (2 waves) per matrix, LDS-distributed
// rotations, tol2 = 1e-16*||A||^2 (V is f32-accumulated).
// ---------------------------------------------------------------------------
__global__ __launch_bounds__(128) void eigh_kernel(const float* __restrict__ Hf,
                                                   float* __restrict__ E_all,
                                                   float* __restrict__ CT_all)
{
    __shared__ double A[NN][NN + 1];
    __shared__ float  V[NN][NN + 1];
    __shared__ double csC[16], csS[16];
    __shared__ int   prC[16], qrC[16];
    __shared__ double redv;
    __shared__ int   rankl[NN];

    const int idx = blockIdx.x;      // b*601 + t
    const int tid = threadIdx.x;
    const float* Hp = Hf + (size_t)idx * (NN * NN);

    for (int e = tid; e < NN * NN; e += 128) {
        A[e >> 5][e & 31] = (double)Hp[e];
        V[e >> 5][e & 31] = ((e >> 5) == (e & 31)) ? 1.f : 0.f;
    }
    __syncthreads();

    if (tid < 64) {                 // original 64-lane mapping -> identical tol2
        double part = 0.0;
        for (int e = tid; e < NN * NN; e += 64) { double v = A[e >> 5][e & 31]; part += v * v; }
        #pragma unroll
        for (int off = 32; off > 0; off >>= 1) part += __shfl_down(part, off);
        if (tid == 0) redv = part;
    }
    __syncthreads();
    const double tol2 = 1e-16 * redv;

    for (int sweep = 0; sweep < 10; ++sweep) {
        for (int r = 0; r < NN - 1; ++r) {
            if (tid < 16) {
                int m = tid, p, q;
                if (m == 0) { p = 0; q = 1 + (r % 31); }
                else { p = 1 + ((m + r) % 31); q = 1 + ((31 - m + r) % 31); }
                double apq = A[p][q];
                double c = 1.0, sn = 0.0;
                if (apq != 0.0) {
                    double theta = 0.5 * (A[q][q] - A[p][p]) / apq;
                    double tt = 1.0 / (fabs(theta) + sqrt(theta * theta + 1.0));
                    if (theta < 0.0) tt = -tt;
                    c = 1.0 / sqrt(tt * tt + 1.0);
                    sn = tt * c;
                }
                csC[m] = c; csS[m] = sn; prC[m] = p; qrC[m] = q;
            }
            __syncthreads();
            #pragma unroll
            for (int it = 0; it < 4; ++it) {          // rows: A <- J^T A (512 tasks)
                int task = tid + it * 128;
                int m = task >> 5, jc = task & 31;
                int p = prC[m], q = qrC[m];
                double c = csC[m], sn = csS[m];
                double ap = A[p][jc], aq = A[q][jc];
                A[p][jc] = c * ap - sn * aq;
                A[q][jc] = sn * ap + c * aq;
            }
            __syncthreads();
            #pragma unroll
            for (int it = 0; it < 8; ++it) {          // cols: A (f64) + V (f32), 1024 tasks
                int task = tid + it * 128;
                int m = (task >> 5) & 15, ir = task & 31;
                int p = prC[m], q = qrC[m];
                if (task < 512) {
                    double c = csC[m], sn = csS[m];
                    double aip = A[ir][p], aiq = A[ir][q];
                    A[ir][p] = c * aip - sn * aiq;
                    A[ir][q] = sn * aip + c * aiq;
                } else {
                    float cf = (float)csC[m], sf = (float)csS[m];
                    float vip = V[ir][p], viq = V[ir][q];
                    V[ir][p] = cf * vip - sf * viq;
                    V[ir][q] = sf * vip + cf * viq;
                }
            }
            __syncthreads();
        }
        if (sweep >= 3) {
            if (tid < 64) {         // original 64-lane mapping -> identical redv
                double o = 0.0;
                for (int e = tid; e < NN * NN; e += 64) {
                    int i2 = e >> 5, j2 = e & 31;
                    double v = A[i2][j2];
                    o += (i2 != j2) ? v * v : 0.0;
                }
                #pragma unroll
                for (int off = 32; off > 0; off >>= 1) o += __shfl_down(o, off);
                if (tid == 0) redv = o;
            }
            __syncthreads();
            if (redv <= tol2) break;
        }
    }
    __syncthreads();

    if (tid < NN) {
        double ei = A[tid][tid];
        int rk = 0;
        for (int j2 = 0; j2 < NN; ++j2) {
            double ej = A[j2][j2];
            rk += (ej < ei || (ej == ei && j2 < tid)) ? 1 : 0;
        }
        rankl[tid] = rk;
        E_all[(size_t)idx * NN + rk] = (float)ei;
    }
    __syncthreads();
    float* ct = CT_all + (size_t)idx * NN * NN;
    for (int e = tid; e < NN * NN; e += 128) {
        int col = e >> 5, m2 = e & 31;
        ct[(size_t)rankl[col] * NN + m2] = V[m2][col];
    }
}

// ---------------------------------------------------------------------------
// Pack weights: Wp[g 8][kb 20][kp 4][12] (10 u + 2 pad, 16B rows; zero pad).
// (R7-proven layout for 8 u-groups of 10.)
// ---------------------------------------------------------------------------
__global__ void wtrans_kernel(const float* __restrict__ W1, const float* __restrict__ b1,
                              const float* __restrict__ W2, const float* __restrict__ W3,
                              const float* __restrict__ b2, const float* __restrict__ b3,
                              const float* __restrict__ W4,
                              float* __restrict__ W2p, float* __restrict__ W3p,
                              float4* __restrict__ L1W4, float4* __restrict__ L1B4,
                              float* __restrict__ bpad)
{
    const int tid = threadIdx.x;
    const int tot = 8 * NKB * 4 * 12;          // 7680
    for (int e = tid; e < tot; e += 256) {
        int g  = e / (NKB * 4 * 12);
        int kb = (e / (4 * 12)) % NKB;
        int kp = (e / 12) & 3;
        int uu = e % 12;
        int u = g * 10 + uu;
        int k = kb * 4 + kp;
        float v2 = 0.f, v3 = 0.f;
        if (uu < 10 && u < NH && k < NH) {
            v2 = W2[u * NH + k];
            v3 = W3[u * NH + k];
        }
        W2p[e] = v2; W3p[e] = v3;
    }
    if (tid < NU) {
        if (tid < NH) {
            const float* w = W1 + tid * 8;
            L1W4[tid] = make_float4(w[0], w[1], w[2], w[7]);
            L1B4[tid] = make_float4(w[3], w[4], w[5], b1[tid]);
            bpad[tid]          = b2[tid];
            bpad[NU + tid]     = b3[tid];
            bpad[2 * NU + tid] = W4[tid];
        } else {
            L1W4[tid] = make_float4(0.f, 0.f, 0.f, 0.f);
            L1B4[tid] = make_float4(0.f, 0.f, 0.f, 0.f);
            bpad[tid] = 0.f; bpad[NU + tid] = 0.f; bpad[2 * NU + tid] = 0.f;
        }
    }
}

// ---------------------------------------------------------------------------
// Phase B persistent kernel. R12 = R11 with CELL-SPLIT MLP (see header).
// Wave w: g = w&7 (10 u's), ch = w>>3 (cell half); lane owns cell
// c = ch*64 + lane. acc[10] scalars. Bit-exact vs R11 per (u,cell).
// ---------------------------------------------------------------------------
__global__ __launch_bounds__(1024) void persist_kernel(
    const float* __restrict__ E_all, const float* __restrict__ CT_all,
    const float* __restrict__ psi0,
    const float* __restrict__ Tarr, const float* __restrict__ ErA,
    const float* __restrict__ ctA, const float* __restrict__ dtA,
    const float* __restrict__ W2p, const float* __restrict__ W3p,
    const float4* __restrict__ L1W4g, const float4* __restrict__ L1B4g,
    const float* __restrict__ bpad, const float* __restrict__ b4v,
    double* __restrict__ part_g, unsigned int* __restrict__ cnt,
    float* __restrict__ out)
{
    extern __shared__ __align__(16) float dyn[];
    float4* L1Wl = (float4*)dyn;                // 80 f4
    float4* L1Bl = L1Wl + NU;                   // 80 f4
    float* cst  = (float*)(L1Bl + NU);          // 80
    float* b2l  = cst + NU;                     // 80
    float* b3l  = b2l + NU;                     // 80
    float* W4l  = b3l + NU;                     // 80
    float* hbuf = W4l + NU;                     // 80*128 = 10240 floats

    __shared__ __align__(16) float CpN[2][NN][NN + 4];
    __shared__ float4 featS[128];               // {DE, ratio, Sv, ex} per cell
    __shared__ float a4b2f[16][128];            // 16 5-u partials per cell
    __shared__ float EL[2][NN];
    __shared__ int   kkL[2][NN];
    __shared__ double phre[NN], phim[NN];
    __shared__ double ppre[4][NN], ppim[4][NN]; // per-column products
    __shared__ double sre[NN], sim[NN];         // sib-summed partials
    __shared__ float phi2l[NN];

    const int tid  = threadIdx.x;
    const int b    = blockIdx.x >> 3;           // sibling sets consecutive
    const int iblk = blockIdx.x & 7;
    const int j0   = iblk * 4;                  // owns columns j0..j0+3
    const int w    = __builtin_amdgcn_readfirstlane(tid >> 6);  // wave id 0..15
    const int g    = w & 7;                     // u-group (10 u's)
    const int ch   = w >> 3;                    // cell half
    const int rg   = tid & 63;
    const int c    = ch * 64 + rg;              // owned cell 0..127
    const int U    = g * 10;

    const float kbt = KBOLTZ * Tarr[b];
    const float er  = ErA[b];
    const float cti = ctA[b];
    const double dtb = (double)dtA[b];
    const float b4s = b4v[0];

    const float4* W2g = (const float4*)(W2p + (size_t)g * (NKB * 48));
    const float4* W3g = (const float4*)(W3p + (size_t)g * (NKB * 48));

    // ---- stage small loop-invariant tables into LDS (once) ----
    if (tid < NU) {
        L1Wl[tid] = L1W4g[tid];
        L1Bl[tid] = L1B4g[tid];
        b2l[tid] = bpad[tid];
        b3l[tid] = bpad[NU + tid];
        W4l[tid] = bpad[2 * NU + tid];
    }
    __syncthreads();
    if (tid < NU) {     // per-b constant part of layer-1 preactivation
        float4 lb = L1Bl[tid];
        cst[tid] = lb.w + lb.x * kbt + lb.y * er + lb.z * cti;
    }

    // ---- prime: C_0, C_1, E[0], E[1]; init phiB; featS + kk for s=1 ----
    {
        const float* c0g = CT_all + (size_t)b * NT1 * NN * NN;
        const float* c1g = c0g + NN * NN;
        for (int e = tid; e < NN * NN; e += 1024) {
            CpN[0][e >> 5][e & 31] = c0g[e];
            CpN[1][e >> 5][e & 31] = c1g[e];
        }
        if (tid < NN) {
            EL[0][tid] = E_all[((size_t)b * NT1 + 0) * NN + tid];
            EL[1][tid] = E_all[((size_t)b * NT1 + 1) * NN + tid];
        }
        __syncthreads();
        if (tid < NN) {
            const int i = tid;
            double acc = 0.0;
            for (int j = 0; j < NN; ++j) acc += (double)CpN[0][i][j] * (double)psi0[b * NN + j];
            phre[i] = acc; phim[i] = 0.0;
            phi2l[i] = (float)(acc * acc);
            if (iblk == 0) {
                float p0 = psi0[b * NN + i];
                out[((size_t)b * 61) * NN + i] = p0 * p0;
            }
        }
        __syncthreads();
        {   // strided Sv for step-1 features (8 lanes per cell)
            const int r = tid >> 3, cc = tid & 7;
            const int i = r & 31, j = j0 + (r >> 5);
            float Sv = 0.f;
            #pragma unroll
            for (int m = cc; m < NN; m += 8)
                Sv += CpN[1][i][m] * CpN[0][j][m];
            Sv += __shfl_xor(Sv, 1); Sv += __shfl_xor(Sv, 2); Sv += __shfl_xor(Sv, 4);
            if (cc == 0) featS[r] = make_float4(0.f, 0.f, Sv, 0.f);
        }
        __syncthreads();
        if (tid < 128) {    // SEQUENTIAL Sv (float4 rows) -> kk, DE, ratio, ex
            const int r = tid, i = r & 31;
            const int j = j0 + (r >> 5);
            const float4* ri = (const float4*)(&CpN[1][i][0]);
            const float4* rj = (const float4*)(&CpN[0][j][0]);
            float svq = 0.f;
            #pragma unroll
            for (int m4 = 0; m4 < 8; ++m4) {
                float4 av = ri[m4], bv = rj[m4];
                svq += av.x * bv.x;
                svq += av.y * bv.y;
                svq += av.z * bv.z;
                svq += av.w * bv.w;
            }
            float v2 = svq * svq;
            int bi = i;
            #pragma unroll
            for (int off = 16; off > 0; off >>= 1) {
                float ov = __shfl_xor(v2, off);
                int   oi = __shfl_xor(bi, off);
                if (ov > v2 || (ov == v2 && oi < bi)) { v2 = ov; bi = oi; }
            }
            if (i == 0) kkL[1][j] = bi;
            const float DE = (i == bi) ? 0.f : (EL[1][i] - EL[0][j]);
            const float Sv = featS[r].z;
            const float p_i = phi2l[i], p_j = phi2l[j];
            const float ratio = (p_j > 0.01f * p_i) ? (p_i / p_j) : 100.f;
            featS[r] = make_float4(DE, ratio, Sv, __expf(DE / kbt));
        }
    }

    for (int t = 1; t <= NSTEPS; ++t) {
        __syncthreads();                        // featS / phi2l visible
        const int cur = t & 1;

        // ---- issue prefetch loads for step t+1 (retire during MLP) ----
        float2 cpre = make_float2(0.f, 0.f);
        float  epre = 0.f;
        if (t < NSTEPS) {
            if (tid < 512) {
                const float* c1g = CT_all + ((size_t)b * NT1 + t + 1) * (NN * NN);
                cpre = ((const float2*)c1g)[tid];
            }
            if (tid < NN) epre = E_all[((size_t)b * NT1 + t + 1) * NN + tid];
        }

        // ---- layer 1 (features -> h1): 10u x 1 cell per thread ----
        {
            float4 f0 = featS[c];
            #pragma unroll
            for (int u = 0; u < 10; ++u) {
                float4 wv = L1Wl[U + u];
                float cc = cst[U + u];
                hbuf[(U + u) * 128 + c] =
                    elu1(cc + wv.x * f0.x + wv.y * f0.y + wv.z * f0.z + wv.w * f0.w);
            }
        }
        __syncthreads();

        // ---- layer 2 (h1 -> h2): scalar hv reads (half hbuf per wave) ----
        float acc[10];
        #pragma unroll
        for (int u = 0; u < 10; ++u) acc[u] = b2l[U + u];
        for (int kb = 0; kb < NKB; ++kb) {
            float4 wv[12];
            float hv[4];
            #pragma unroll
            for (int m = 0; m < 12; ++m) wv[m] = W2g[kb * 12 + m];   // uniform -> s_load
            #pragma unroll
            for (int kk = 0; kk < 4; ++kk)
                hv[kk] = hbuf[(kb * 4 + kk) * 128 + c];
            #pragma unroll
            for (int kk = 0; kk < 4; ++kk) {
                const float* wf = (const float*)&wv[kk * 3];
                #pragma unroll
                for (int u = 0; u < 10; ++u) acc[u] += wf[u] * hv[kk];
            }
        }
        __syncthreads();    // all reads of h1 done before overwriting hbuf
        #pragma unroll
        for (int u = 0; u < 10; ++u) hbuf[(U + u) * 128 + c] = elu1(acc[u]);
        __syncthreads();

        // ---- layer 3 (h2 -> h3 in registers) ----
        #pragma unroll
        for (int u = 0; u < 10; ++u) acc[u] = b3l[U + u];
        for (int kb = 0; kb < NKB; ++kb) {
            float4 wv[12];
            float hv[4];
            #pragma unroll
            for (int m = 0; m < 12; ++m) wv[m] = W3g[kb * 12 + m];   // uniform -> s_load
            #pragma unroll
            for (int kk = 0; kk < 4; ++kk)
                hv[kk] = hbuf[(kb * 4 + kk) * 128 + c];
            #pragma unroll
            for (int kk = 0; kk < 4; ++kk) {
                const float* wf = (const float*)&wv[kk * 3];
                #pragma unroll
                for (int u = 0; u < 10; ++u) acc[u] += wf[u] * hv[kk];
            }
        }
        // ---- layer 4 partials: TWO 5-u partials (match R9's 16-group order)
        {
            float p4a = 0.f, p4b = 0.f;
            #pragma unroll
            for (int u = 0; u < 5; ++u) p4a += W4l[U + u] * elu1(acc[u]);
            #pragma unroll
            for (int u = 5; u < 10; ++u) p4b += W4l[U + u] * elu1(acc[u]);
            a4b2f[2 * g][c] = p4a;
            a4b2f[2 * g + 1][c] = p4b;
        }
        __syncthreads();

        // ---- finalize corr, IN-REGISTER column correction, per-column
        //      complex products into LDS (pre-barrier partial reduction) ----
        if (tid < 128) {
            const int r = tid;
            const int i = r & 31;
            const int jj = r >> 5;              // 0..3
            const int j = j0 + jj;
            float a4 = b4s;
            #pragma unroll
            for (int gg = 0; gg < 16; ++gg) a4 += a4b2f[gg][r];
            const float corr = elu1(a4) + 1.f;
            float s2v = featS[r].z * corr;
            const int kj = kkL[cur][j];
            double v = (double)s2v;
            double cd = (i == kj) ? 0.0 : v * v;        // reduce over i (32 lanes)
            cd += __shfl_xor(cd, 1);  cd += __shfl_xor(cd, 2);
            cd += __shfl_xor(cd, 4);  cd += __shfl_xor(cd, 8);
            cd += __shfl_xor(cd, 16);
            if (i == kj) {
                double nrm = fabs(v); nrm = (nrm > 0.0) ? nrm : 1.0;
                double rem = 1.0 - cd;
                v = (rem > 0.0) ? (sqrt(rem) * v / nrm) : v;
                v = (double)(float)v;           // keep f32 rounding as before
            }
            ppre[jj][i] = v * phre[j];
            ppim[jj][i] = v * phim[j];
        }

        // ---- commit prefetch into dead ping-pong slots ----
        if (t < NSTEPS) {
            if (tid < 512) {
                const int e0 = tid * 2;
                CpN[1 - cur][e0 >> 5][e0 & 31] = cpre.x;
                CpN[1 - cur][e0 >> 5][(e0 & 31) + 1] = cpre.y;
            }
            if (tid < NN) EL[1 - cur][tid] = epre;
        }
        __syncthreads();

        // ---- sum own 4 columns, coherent-store partials, signal (wave 0) ----
        if (tid < 32) {
            const int i = tid;
            double pr = ((ppre[0][i] + ppre[1][i]) + ppre[2][i]) + ppre[3][i];
            double pi = ((ppim[0][i] + ppim[1][i]) + ppim[2][i]) + ppim[3][i];
            double* pg = part_g + ((size_t)cur * NB + b) * 512;
            __hip_atomic_store(&pg[i * 8 + iblk], pr,
                               __ATOMIC_RELAXED, __HIP_MEMORY_SCOPE_AGENT);
            __hip_atomic_store(&pg[256 + i * 8 + iblk], pi,
                               __ATOMIC_RELAXED, __HIP_MEMORY_SCOPE_AGENT);
            asm volatile("s_waitcnt vmcnt(0)" ::: "memory");    // drain (wave 0)
            if (tid == 0)
                __hip_atomic_fetch_add(cnt + (size_t)b * NSTEPS + (t - 1), 1u,
                                       __ATOMIC_RELAXED, __HIP_MEMORY_SCOPE_AGENT);
        }

        // ---- strided Sv for t+1 features — hidden inside the spin window ----
        if (t < NSTEPS) {
            const int curS = 1 - cur;
            const int r = tid >> 3, cc = tid & 7;
            const int i = r & 31, j = j0 + (r >> 5);
            float Sv = 0.f;
            #pragma unroll
            for (int m = cc; m < NN; m += 8)
                Sv += CpN[curS][i][m] * CpN[1 - curS][j][m];
            Sv += __shfl_xor(Sv, 1); Sv += __shfl_xor(Sv, 2); Sv += __shfl_xor(Sv, 4);
            if (cc == 0) featS[r] = make_float4(0.f, 0.f, Sv, 0.f);
        }

        // ---- sibling barrier: wait for 8 arrivals ----
        if (tid == 0) {
            const unsigned int* cc = cnt + (size_t)b * NSTEPS + (t - 1);
            while (__hip_atomic_load(cc, __ATOMIC_RELAXED, __HIP_MEMORY_SCOPE_AGENT)
                   < (unsigned)NIB) {
                __builtin_amdgcn_s_sleep(2);    // ~128cyc between polls
            }
        }
        __syncthreads();

        // ---- gather partials: tid = comp*256 + i*8 + sib; 3-level sib-sum ----
        if (tid < 512) {
            const double* pg = part_g + ((size_t)cur * NB + b) * 512;
            double v = __hip_atomic_load(&pg[tid], __ATOMIC_RELAXED,
                                         __HIP_MEMORY_SCOPE_AGENT);
            v += __shfl_xor(v, 1); v += __shfl_xor(v, 2); v += __shfl_xor(v, 4);
            if ((tid & 7) == 0) {
                const int i = (tid >> 3) & 31;
                if (tid < 256) sre[i] = v; else sim[i] = v;
            }
        }
        __syncthreads();

        // ---- fused phase + normalize (wave 0) || kk for t+1 (waves 4-5,
        //      SEQUENTIAL float4-row Sv -> bit-exact) ----
        if (tid < NN) {
            const int ii = tid;
            double are = sre[ii], aim = sim[ii];
            double th = (double)EL[cur][ii] * (TWO_PI * ICM2IFS) * dtb;   // |th| < ~0.1
            double x2 = th * th;        // poly sincos, |err| ~1e-16 at this range
            double sph = th * (1.0 + x2 * (-1.0 / 6.0 + x2 * (1.0 / 120.0 + x2 * (-1.0 / 5040.0 + x2 * (1.0 / 362880.0)))));
            double cph = 1.0 + x2 * (-0.5 + x2 * (1.0 / 24.0 + x2 * (-1.0 / 720.0 + x2 * (1.0 / 40320.0))));
            double nre = cph * are + sph * aim;            // exp(-iEw) = c - i s
            double nim = cph * aim - sph * are;
            double v = nre * nre + nim * nim;
            double s = v;
            s += __shfl_xor(s, 1); s += __shfl_xor(s, 2); s += __shfl_xor(s, 4);
            s += __shfl_xor(s, 8); s += __shfl_xor(s, 16);
            double sc = 1.0 / sqrt(s);
            double nr = nre * sc, ni = nim * sc;
            phre[ii] = nr; phim[ii] = ni;
            phi2l[ii] = (float)(nr * nr + ni * ni);
        } else if (t < NSTEPS && tid >= 256 && tid < 384) {
            const int r = tid - 256;
            const int i = r & 31;
            const int j = j0 + (r >> 5);
            const int curS = 1 - cur;
            const float4* ri = (const float4*)(&CpN[curS][i][0]);
            const float4* rj = (const float4*)(&CpN[cur][j][0]);
            float svq = 0.f;
            #pragma unroll
            for (int m4 = 0; m4 < 8; ++m4) {
                float4 av = ri[m4], bv = rj[m4];
                svq += av.x * bv.x;
                svq += av.y * bv.y;
                svq += av.z * bv.z;
                svq += av.w * bv.w;
            }
            float v2 = svq * svq;
            int bi = i;
            #pragma unroll
            for (int off = 16; off > 0; off >>= 1) {
                float ov = __shfl_xor(v2, off);
                int   oi = __shfl_xor(bi, off);
                if (ov > v2 || (ov == v2 && oi < bi)) { v2 = ov; bi = oi; }
            }
            if (i == 0) kkL[curS][j] = bi;
            const float DE = (i == bi) ? 0.f : (EL[curS][i] - EL[cur][j]);
            featS[r].x = DE;
            featS[r].w = __expf(DE / kbt);
        }
        __syncthreads();

        // ---- ploc (every NSI steps, 4 rows per sibling) + ratio finalize ----
        if ((t % NSI) == 0 && tid < 64) {
            const int ii = iblk * 4 + (tid >> 4), l = tid & 15;
            double are = 0.0, aim = 0.0;
            #pragma unroll
            for (int jj = l; jj < NN; jj += 16) {
                double cij = (double)CpN[cur][jj][ii];   // C_t[i][j] = CT_t[j][i]
                are += cij * phre[jj]; aim += cij * phim[jj];
            }
            are += __shfl_xor(are, 1); aim += __shfl_xor(aim, 1);
            are += __shfl_xor(are, 2); aim += __shfl_xor(aim, 2);
            are += __shfl_xor(are, 4); aim += __shfl_xor(aim, 4);
            are += __shfl_xor(are, 8); aim += __shfl_xor(aim, 8);
            if (l == 0)
                out[((size_t)b * 61 + t / NSI) * NN + ii] = (float)(are * are + aim * aim);
        }
        if (t < NSTEPS && tid < 128) {     // ratio for t+1 (needs fresh phi2l)
            const int i = tid & 31, j = j0 + (tid >> 5);
            const float p_i = phi2l[i], p_j = phi2l[j];
            featS[tid].y = (p_j > 0.01f * p_i) ? (p_i / p_j) : 100.f;
        }
    }
}

// ---------------------------------------------------------------------------
extern "C" void kernel_launch(void* const* d_in, const int* in_sizes, int n_in,
                              void* d_out, int out_size, void* d_ws, size_t ws_size,
                              hipStream_t stream)
{
    const float* Tarr = (const float*)d_in[0];
    const float* ErA  = (const float*)d_in[1];
    const float* ctA  = (const float*)d_in[2];
    const float* dtA  = (const float*)d_in[4];
    const float* psi0 = (const float*)d_in[6];
    const float* Hf   = (const float*)d_in[7];
    const float* W1   = (const float*)d_in[8];
    const float* b1   = (const float*)d_in[9];
    const float* W2   = (const float*)d_in[10];
    const float* b2   = (const float*)d_in[11];
    const float* W3   = (const float*)d_in[12];
    const float* b3   = (const float*)d_in[13];
    const float* W4   = (const float*)d_in[14];
    const float* b4   = (const float*)d_in[15];

    unsigned int* cnt = (unsigned int*)d_ws;                    // 32*600 counters
    float* E_all  = (float*)(cnt + (size_t)NB * NSTEPS);        // 32*601*32
    float* CT_all = E_all + (size_t)NB * NT1 * NN;              // 32*601*32*32
    float* W2p    = CT_all + (size_t)NB * NT1 * NN * NN;        // 7680
    float* W3p    = W2p + 8 * NKB * 48;                         // 7680
    float4* L1W4  = (float4*)(W3p + 8 * NKB * 48);              // 80 f4
    float4* L1B4  = L1W4 + NU;                                  // 80 f4
    float* bpad   = (float*)(L1B4 + NU);                        // 3*80
    double* part_g = (double*)(bpad + 3 * NU);                  // 2*32*512 f64 (256KB)
    float* outp   = (float*)d_out;

    hipMemsetAsync(cnt, 0, (size_t)NB * NSTEPS * sizeof(unsigned int), stream);
    eigh_kernel<<<NB * NT1, 128, 0, stream>>>(Hf, E_all, CT_all);
    wtrans_kernel<<<1, 256, 0, stream>>>(W1, b1, W2, W3, b2, b3, W4,
                                         W2p, W3p, L1W4, L1B4, bpad);

    // dyn LDS: two f4 tables (80 each) + 4x80 biases + hbuf 80*128
    const size_t dynf = (size_t)(8 * NU) + 4 * NU + NU * 128;
    persist_kernel<<<NB * NIB, 1024, dynf * sizeof(float), stream>>>(E_all, CT_all,
        psi0, Tarr, ErA, ctA, dtA, W2p, W3p, L1W4, L1B4, bpad, b4,
        part_g, cnt, outp);
}

// Round 13
// 101176.727 us; speedup vs baseline: 1.0183x; 1.0183x over previous
//
#include <hip/hip_runtime.h>
#include <math.h>

// R13 = R12 with ONE change: __launch_bounds__(1024, 4) on persist_kernel.
// R12's 103ms regression was scratch spill (FETCH 174GB / WRITE 186GB,
// VALUBusy 26%): with no min-waves arg the compiler targeted 2 blocks/CU
// -> 64-VGPR cap, but the cell-split working set (wv[12] f4 = 48 + acc[10]
// + hv[4] + addressing ~ 85) needs more. (1024, 4) = 4 waves/SIMD = our one
// 16-wave block/CU -> cap 128 VGPR -> no spill. Grid is 256 blocks = 1/CU,
// so nothing is lost. All else byte-identical to R12 (cell-split MLP,
// bit-exact kk fold, fused tails).

#define NB 32
#define NN 32
#define NSTEPS 600
#define NT1 601
#define NSI 10
#define NH 75
#define NU 80      // padded u
#define NKB 20     // padded k-blocks of 4 (k padded 75 -> 80)
#define NIB 8      // sibling blocks per batch element (grid = 256 = #CUs)

#define ICM2IFS 2.99792458e-05
#define KBOLTZ 0.6950389f
#define TWO_PI 6.283185307179586476925286766559

__device__ __forceinline__ float elu1(float x) { return x > 0.f ? x : (__expf(x) - 1.f); }

// ---------------------------------------------------------------------------
// Phase A: batched 32x32 symmetric eigensolver (parallel cyclic Jacobi).
// R9-proven version: 128 threads (2 waves) per matrix, LDS-distributed
// rotations, tol2 = 1e-16*||A||^2 (V is f32-accumulated).
// ---------------------------------------------------------------------------
__global__ __launch_bounds__(128) void eigh_kernel(const float* __restrict__ Hf,
                                                   float* __restrict__ E_all,
                                                   float* __restrict__ CT_all)
{
    __shared__ double A[NN][NN + 1];
    __shared__ float  V[NN][NN + 1];
    __shared__ double csC[16], csS[16];
    __shared__ int   prC[16], qrC[16];
    __shared__ double redv;
    __shared__ int   rankl[NN];

    const int idx = blockIdx.x;      // b*601 + t
    const int tid = threadIdx.x;
    const float* Hp = Hf + (size_t)idx * (NN * NN);

    for (int e = tid; e < NN * NN; e += 128) {
        A[e >> 5][e & 31] = (double)Hp[e];
        V[e >> 5][e & 31] = ((e >> 5) == (e & 31)) ? 1.f : 0.f;
    }
    __syncthreads();

    if (tid < 64) {                 // original 64-lane mapping -> identical tol2
        double part = 0.0;
        for (int e = tid; e < NN * NN; e += 64) { double v = A[e >> 5][e & 31]; part += v * v; }
        #pragma unroll
        for (int off = 32; off > 0; off >>= 1) part += __shfl_down(part, off);
        if (tid == 0) redv = part;
    }
    __syncthreads();
    const double tol2 = 1e-16 * redv;

    for (int sweep = 0; sweep < 10; ++sweep) {
        for (int r = 0; r < NN - 1; ++r) {
            if (tid < 16) {
                int m = tid, p, q;
                if (m == 0) { p = 0; q = 1 + (r % 31); }
                else { p = 1 + ((m + r) % 31); q = 1 + ((31 - m + r) % 31); }
                double apq = A[p][q];
                double c = 1.0, sn = 0.0;
                if (apq != 0.0) {
                    double theta = 0.5 * (A[q][q] - A[p][p]) / apq;
                    double tt = 1.0 / (fabs(theta) + sqrt(theta * theta + 1.0));
                    if (theta < 0.0) tt = -tt;
                    c = 1.0 / sqrt(tt * tt + 1.0);
                    sn = tt * c;
                }
                csC[m] = c; csS[m] = sn; prC[m] = p; qrC[m] = q;
            }
            __syncthreads();
            #pragma unroll
            for (int it = 0; it < 4; ++it) {          // rows: A <- J^T A (512 tasks)
                int task = tid + it * 128;
                int m = task >> 5, jc = task & 31;
                int p = prC[m], q = qrC[m];
                double c = csC[m], sn = csS[m];
                double ap = A[p][jc], aq = A[q][jc];
                A[p][jc] = c * ap - sn * aq;
                A[q][jc] = sn * ap + c * aq;
            }
            __syncthreads();
            #pragma unroll
            for (int it = 0; it < 8; ++it) {          // cols: A (f64) + V (f32), 1024 tasks
                int task = tid + it * 128;
                int m = (task >> 5) & 15, ir = task & 31;
                int p = prC[m], q = qrC[m];
                if (task < 512) {
                    double c = csC[m], sn = csS[m];
                    double aip = A[ir][p], aiq = A[ir][q];
                    A[ir][p] = c * aip - sn * aiq;
                    A[ir][q] = sn * aip + c * aiq;
                } else {
                    float cf = (float)csC[m], sf = (float)csS[m];
                    float vip = V[ir][p], viq = V[ir][q];
                    V[ir][p] = cf * vip - sf * viq;
                    V[ir][q] = sf * vip + cf * viq;
                }
            }
            __syncthreads();
        }
        if (sweep >= 3) {
            if (tid < 64) {         // original 64-lane mapping -> identical redv
                double o = 0.0;
                for (int e = tid; e < NN * NN; e += 64) {
                    int i2 = e >> 5, j2 = e & 31;
                    double v = A[i2][j2];
                    o += (i2 != j2) ? v * v : 0.0;
                }
                #pragma unroll
                for (int off = 32; off > 0; off >>= 1) o += __shfl_down(o, off);
                if (tid == 0) redv = o;
            }
            __syncthreads();
            if (redv <= tol2) break;
        }
    }
    __syncthreads();

    if (tid < NN) {
        double ei = A[tid][tid];
        int rk = 0;
        for (int j2 = 0; j2 < NN; ++j2) {
            double ej = A[j2][j2];
            rk += (ej < ei || (ej == ei && j2 < tid)) ? 1 : 0;
        }
        rankl[tid] = rk;
        E_all[(size_t)idx * NN + rk] = (float)ei;
    }
    __syncthreads();
    float* ct = CT_all + (size_t)idx * NN * NN;
    for (int e = tid; e < NN * NN; e += 128) {
        int col = e >> 5, m2 = e & 31;
        ct[(size_t)rankl[col] * NN + m2] = V[m2][col];
    }
}

// ---------------------------------------------------------------------------
// Pack weights: Wp[g 8][kb 20][kp 4][12] (10 u + 2 pad, 16B rows; zero pad).
// ---------------------------------------------------------------------------
__global__ void wtrans_kernel(const float* __restrict__ W1, const float* __restrict__ b1,
                              const float* __restrict__ W2, const float* __restrict__ W3,
                              const float* __restrict__ b2, const float* __restrict__ b3,
                              const float* __restrict__ W4,
                              float* __restrict__ W2p, float* __restrict__ W3p,
                              float4* __restrict__ L1W4, float4* __restrict__ L1B4,
                              float* __restrict__ bpad)
{
    const int tid = threadIdx.x;
    const int tot = 8 * NKB * 4 * 12;          // 7680
    for (int e = tid; e < tot; e += 256) {
        int g  = e / (NKB * 4 * 12);
        int kb = (e / (4 * 12)) % NKB;
        int kp = (e / 12) & 3;
        int uu = e % 12;
        int u = g * 10 + uu;
        int k = kb * 4 + kp;
        float v2 = 0.f, v3 = 0.f;
        if (uu < 10 && u < NH && k < NH) {
            v2 = W2[u * NH + k];
            v3 = W3[u * NH + k];
        }
        W2p[e] = v2; W3p[e] = v3;
    }
    if (tid < NU) {
        if (tid < NH) {
            const float* w = W1 + tid * 8;
            L1W4[tid] = make_float4(w[0], w[1], w[2], w[7]);
            L1B4[tid] = make_float4(w[3], w[4], w[5], b1[tid]);
            bpad[tid]          = b2[tid];
            bpad[NU + tid]     = b3[tid];
            bpad[2 * NU + tid] = W4[tid];
        } else {
            L1W4[tid] = make_float4(0.f, 0.f, 0.f, 0.f);
            L1B4[tid] = make_float4(0.f, 0.f, 0.f, 0.f);
            bpad[tid] = 0.f; bpad[NU + tid] = 0.f; bpad[2 * NU + tid] = 0.f;
        }
    }
}

// ---------------------------------------------------------------------------
// Phase B persistent kernel. Cell-split MLP (R12) at the CORRECT register
// budget: __launch_bounds__(1024, 4) -> 128-VGPR cap, no spill.
// Wave w: g = w&7 (10 u's), ch = w>>3 (cell half); lane owns cell
// c = ch*64 + lane. acc[10] scalars. Bit-exact vs R11 per (u,cell).
// ---------------------------------------------------------------------------
__global__ __launch_bounds__(1024, 4) void persist_kernel(
    const float* __restrict__ E_all, const float* __restrict__ CT_all,
    const float* __restrict__ psi0,
    const float* __restrict__ Tarr, const float* __restrict__ ErA,
    const float* __restrict__ ctA, const float* __restrict__ dtA,
    const float* __restrict__ W2p, const float* __restrict__ W3p,
    const float4* __restrict__ L1W4g, const float4* __restrict__ L1B4g,
    const float* __restrict__ bpad, const float* __restrict__ b4v,
    double* __restrict__ part_g, unsigned int* __restrict__ cnt,
    float* __restrict__ out)
{
    extern __shared__ __align__(16) float dyn[];
    float4* L1Wl = (float4*)dyn;                // 80 f4
    float4* L1Bl = L1Wl + NU;                   // 80 f4
    float* cst  = (float*)(L1Bl + NU);          // 80
    float* b2l  = cst + NU;                     // 80
    float* b3l  = b2l + NU;                     // 80
    float* W4l  = b3l + NU;                     // 80
    float* hbuf = W4l + NU;                     // 80*128 = 10240 floats

    __shared__ __align__(16) float CpN[2][NN][NN + 4];
    __shared__ float4 featS[128];               // {DE, ratio, Sv, ex} per cell
    __shared__ float a4b2f[16][128];            // 16 5-u partials per cell
    __shared__ float EL[2][NN];
    __shared__ int   kkL[2][NN];
    __shared__ double phre[NN], phim[NN];
    __shared__ double ppre[4][NN], ppim[4][NN]; // per-column products
    __shared__ double sre[NN], sim[NN];         // sib-summed partials
    __shared__ float phi2l[NN];

    const int tid  = threadIdx.x;
    const int b    = blockIdx.x >> 3;           // sibling sets consecutive
    const int iblk = blockIdx.x & 7;
    const int j0   = iblk * 4;                  // owns columns j0..j0+3
    const int w    = __builtin_amdgcn_readfirstlane(tid >> 6);  // wave id 0..15
    const int g    = w & 7;                     // u-group (10 u's)
    const int ch   = w >> 3;                    // cell half
    const int rg   = tid & 63;
    const int c    = ch * 64 + rg;              // owned cell 0..127
    const int U    = g * 10;

    const float kbt = KBOLTZ * Tarr[b];
    const float er  = ErA[b];
    const float cti = ctA[b];
    const double dtb = (double)dtA[b];
    const float b4s = b4v[0];

    const float4* W2g = (const float4*)(W2p + (size_t)g * (NKB * 48));
    const float4* W3g = (const float4*)(W3p + (size_t)g * (NKB * 48));

    // ---- stage small loop-invariant tables into LDS (once) ----
    if (tid < NU) {
        L1Wl[tid] = L1W4g[tid];
        L1Bl[tid] = L1B4g[tid];
        b2l[tid] = bpad[tid];
        b3l[tid] = bpad[NU + tid];
        W4l[tid] = bpad[2 * NU + tid];
    }
    __syncthreads();
    if (tid < NU) {     // per-b constant part of layer-1 preactivation
        float4 lb = L1Bl[tid];
        cst[tid] = lb.w + lb.x * kbt + lb.y * er + lb.z * cti;
    }

    // ---- prime: C_0, C_1, E[0], E[1]; init phiB; featS + kk for s=1 ----
    {
        const float* c0g = CT_all + (size_t)b * NT1 * NN * NN;
        const float* c1g = c0g + NN * NN;
        for (int e = tid; e < NN * NN; e += 1024) {
            CpN[0][e >> 5][e & 31] = c0g[e];
            CpN[1][e >> 5][e & 31] = c1g[e];
        }
        if (tid < NN) {
            EL[0][tid] = E_all[((size_t)b * NT1 + 0) * NN + tid];
            EL[1][tid] = E_all[((size_t)b * NT1 + 1) * NN + tid];
        }
        __syncthreads();
        if (tid < NN) {
            const int i = tid;
            double acc = 0.0;
            for (int j = 0; j < NN; ++j) acc += (double)CpN[0][i][j] * (double)psi0[b * NN + j];
            phre[i] = acc; phim[i] = 0.0;
            phi2l[i] = (float)(acc * acc);
            if (iblk == 0) {
                float p0 = psi0[b * NN + i];
                out[((size_t)b * 61) * NN + i] = p0 * p0;
            }
        }
        __syncthreads();
        {   // strided Sv for step-1 features (8 lanes per cell)
            const int r = tid >> 3, cc = tid & 7;
            const int i = r & 31, j = j0 + (r >> 5);
            float Sv = 0.f;
            #pragma unroll
            for (int m = cc; m < NN; m += 8)
                Sv += CpN[1][i][m] * CpN[0][j][m];
            Sv += __shfl_xor(Sv, 1); Sv += __shfl_xor(Sv, 2); Sv += __shfl_xor(Sv, 4);
            if (cc == 0) featS[r] = make_float4(0.f, 0.f, Sv, 0.f);
        }
        __syncthreads();
        if (tid < 128) {    // SEQUENTIAL Sv (float4 rows) -> kk, DE, ratio, ex
            const int r = tid, i = r & 31;
            const int j = j0 + (r >> 5);
            const float4* ri = (const float4*)(&CpN[1][i][0]);
            const float4* rj = (const float4*)(&CpN[0][j][0]);
            float svq = 0.f;
            #pragma unroll
            for (int m4 = 0; m4 < 8; ++m4) {
                float4 av = ri[m4], bv = rj[m4];
                svq += av.x * bv.x;
                svq += av.y * bv.y;
                svq += av.z * bv.z;
                svq += av.w * bv.w;
            }
            float v2 = svq * svq;
            int bi = i;
            #pragma unroll
            for (int off = 16; off > 0; off >>= 1) {
                float ov = __shfl_xor(v2, off);
                int   oi = __shfl_xor(bi, off);
                if (ov > v2 || (ov == v2 && oi < bi)) { v2 = ov; bi = oi; }
            }
            if (i == 0) kkL[1][j] = bi;
            const float DE = (i == bi) ? 0.f : (EL[1][i] - EL[0][j]);
            const float Sv = featS[r].z;
            const float p_i = phi2l[i], p_j = phi2l[j];
            const float ratio = (p_j > 0.01f * p_i) ? (p_i / p_j) : 100.f;
            featS[r] = make_float4(DE, ratio, Sv, __expf(DE / kbt));
        }
    }

    for (int t = 1; t <= NSTEPS; ++t) {
        __syncthreads();                        // featS / phi2l visible
        const int cur = t & 1;

        // ---- issue prefetch loads for step t+1 (retire during MLP) ----
        float2 cpre = make_float2(0.f, 0.f);
        float  epre = 0.f;
        if (t < NSTEPS) {
            if (tid < 512) {
                const float* c1g = CT_all + ((size_t)b * NT1 + t + 1) * (NN * NN);
                cpre = ((const float2*)c1g)[tid];
            }
            if (tid < NN) epre = E_all[((size_t)b * NT1 + t + 1) * NN + tid];
        }

        // ---- layer 1 (features -> h1): 10u x 1 cell per thread ----
        {
            float4 f0 = featS[c];
            #pragma unroll
            for (int u = 0; u < 10; ++u) {
                float4 wv = L1Wl[U + u];
                float cc = cst[U + u];
                hbuf[(U + u) * 128 + c] =
                    elu1(cc + wv.x * f0.x + wv.y * f0.y + wv.z * f0.z + wv.w * f0.w);
            }
        }
        __syncthreads();

        // ---- layer 2 (h1 -> h2): scalar hv reads (half hbuf per wave) ----
        float acc[10];
        #pragma unroll
        for (int u = 0; u < 10; ++u) acc[u] = b2l[U + u];
        for (int kb = 0; kb < NKB; ++kb) {
            float4 wv[12];
            float hv[4];
            #pragma unroll
            for (int m = 0; m < 12; ++m) wv[m] = W2g[kb * 12 + m];   // uniform -> s_load
            #pragma unroll
            for (int kk = 0; kk < 4; ++kk)
                hv[kk] = hbuf[(kb * 4 + kk) * 128 + c];
            #pragma unroll
            for (int kk = 0; kk < 4; ++kk) {
                const float* wf = (const float*)&wv[kk * 3];
                #pragma unroll
                for (int u = 0; u < 10; ++u) acc[u] += wf[u] * hv[kk];
            }
        }
        __syncthreads();    // all reads of h1 done before overwriting hbuf
        #pragma unroll
        for (int u = 0; u < 10; ++u) hbuf[(U + u) * 128 + c] = elu1(acc[u]);
        __syncthreads();

        // ---- layer 3 (h2 -> h3 in registers) ----
        #pragma unroll
        for (int u = 0; u < 10; ++u) acc[u] = b3l[U + u];
        for (int kb = 0; kb < NKB; ++kb) {
            float4 wv[12];
            float hv[4];
            #pragma unroll
            for (int m = 0; m < 12; ++m) wv[m] = W3g[kb * 12 + m];   // uniform -> s_load
            #pragma unroll
            for (int kk = 0; kk < 4; ++kk)
                hv[kk] = hbuf[(kb * 4 + kk) * 128 + c];
            #pragma unroll
            for (int kk = 0; kk < 4; ++kk) {
                const float* wf = (const float*)&wv[kk * 3];
                #pragma unroll
                for (int u = 0; u < 10; ++u) acc[u] += wf[u] * hv[kk];
            }
        }
        // ---- layer 4 partials: TWO 5-u partials (match R9's 16-group order)
        {
            float p4a = 0.f, p4b = 0.f;
            #pragma unroll
            for (int u = 0; u < 5; ++u) p4a += W4l[U + u] * elu1(acc[u]);
            #pragma unroll
            for (int u = 5; u < 10; ++u) p4b += W4l[U + u] * elu1(acc[u]);
            a4b2f[2 * g][c] = p4a;
            a4b2f[2 * g + 1][c] = p4b;
        }
        __syncthreads();

        // ---- finalize corr, IN-REGISTER column correction, per-column
        //      complex products into LDS (pre-barrier partial reduction) ----
        if (tid < 128) {
            const int r = tid;
            const int i = r & 31;
            const int jj = r >> 5;              // 0..3
            const int j = j0 + jj;
            float a4 = b4s;
            #pragma unroll
            for (int gg = 0; gg < 16; ++gg) a4 += a4b2f[gg][r];
            const float corr = elu1(a4) + 1.f;
            float s2v = featS[r].z * corr;
            const int kj = kkL[cur][j];
            double v = (double)s2v;
            double cd = (i == kj) ? 0.0 : v * v;        // reduce over i (32 lanes)
            cd += __shfl_xor(cd, 1);  cd += __shfl_xor(cd, 2);
            cd += __shfl_xor(cd, 4);  cd += __shfl_xor(cd, 8);
            cd += __shfl_xor(cd, 16);
            if (i == kj) {
                double nrm = fabs(v); nrm = (nrm > 0.0) ? nrm : 1.0;
                double rem = 1.0 - cd;
                v = (rem > 0.0) ? (sqrt(rem) * v / nrm) : v;
                v = (double)(float)v;           // keep f32 rounding as before
            }
            ppre[jj][i] = v * phre[j];
            ppim[jj][i] = v * phim[j];
        }

        // ---- commit prefetch into dead ping-pong slots ----
        if (t < NSTEPS) {
            if (tid < 512) {
                const int e0 = tid * 2;
                CpN[1 - cur][e0 >> 5][e0 & 31] = cpre.x;
                CpN[1 - cur][e0 >> 5][(e0 & 31) + 1] = cpre.y;
            }
            if (tid < NN) EL[1 - cur][tid] = epre;
        }
        __syncthreads();

        // ---- sum own 4 columns, coherent-store partials, signal (wave 0) ----
        if (tid < 32) {
            const int i = tid;
            double pr = ((ppre[0][i] + ppre[1][i]) + ppre[2][i]) + ppre[3][i];
            double pi = ((ppim[0][i] + ppim[1][i]) + ppim[2][i]) + ppim[3][i];
            double* pg = part_g + ((size_t)cur * NB + b) * 512;
            __hip_atomic_store(&pg[i * 8 + iblk], pr,
                               __ATOMIC_RELAXED, __HIP_MEMORY_SCOPE_AGENT);
            __hip_atomic_store(&pg[256 + i * 8 + iblk], pi,
                               __ATOMIC_RELAXED, __HIP_MEMORY_SCOPE_AGENT);
            asm volatile("s_waitcnt vmcnt(0)" ::: "memory");    // drain (wave 0)
            if (tid == 0)
                __hip_atomic_fetch_add(cnt + (size_t)b * NSTEPS + (t - 1), 1u,
                                       __ATOMIC_RELAXED, __HIP_MEMORY_SCOPE_AGENT);
        }

        // ---- strided Sv for t+1 features — hidden inside the spin window ----
        if (t < NSTEPS) {
            const int curS = 1 - cur;
            const int r = tid >> 3, cc = tid & 7;
            const int i = r & 31, j = j0 + (r >> 5);
            float Sv = 0.f;
            #pragma unroll
            for (int m = cc; m < NN; m += 8)
                Sv += CpN[curS][i][m] * CpN[1 - curS][j][m];
            Sv += __shfl_xor(Sv, 1); Sv += __shfl_xor(Sv, 2); Sv += __shfl_xor(Sv, 4);
            if (cc == 0) featS[r] = make_float4(0.f, 0.f, Sv, 0.f);
        }

        // ---- sibling barrier: wait for 8 arrivals ----
        if (tid == 0) {
            const unsigned int* cc = cnt + (size_t)b * NSTEPS + (t - 1);
            while (__hip_atomic_load(cc, __ATOMIC_RELAXED, __HIP_MEMORY_SCOPE_AGENT)
                   < (unsigned)NIB) {
                __builtin_amdgcn_s_sleep(2);    // ~128cyc between polls
            }
        }
        __syncthreads();

        // ---- gather partials: tid = comp*256 + i*8 + sib; 3-level sib-sum ----
        if (tid < 512) {
            const double* pg = part_g + ((size_t)cur * NB + b) * 512;
            double v = __hip_atomic_load(&pg[tid], __ATOMIC_RELAXED,
                                         __HIP_MEMORY_SCOPE_AGENT);
            v += __shfl_xor(v, 1); v += __shfl_xor(v, 2); v += __shfl_xor(v, 4);
            if ((tid & 7) == 0) {
                const int i = (tid >> 3) & 31;
                if (tid < 256) sre[i] = v; else sim[i] = v;
            }
        }
        __syncthreads();

        // ---- fused phase + normalize (wave 0) || kk for t+1 (waves 4-5,
        //      SEQUENTIAL float4-row Sv -> bit-exact) ----
        if (tid < NN) {
            const int ii = tid;
            double are = sre[ii], aim = sim[ii];
            double th = (double)EL[cur][ii] * (TWO_PI * ICM2IFS) * dtb;   // |th| < ~0.1
            double x2 = th * th;        // poly sincos, |err| ~1e-16 at this range
            double sph = th * (1.0 + x2 * (-1.0 / 6.0 + x2 * (1.0 / 120.0 + x2 * (-1.0 / 5040.0 + x2 * (1.0 / 362880.0)))));
            double cph = 1.0 + x2 * (-0.5 + x2 * (1.0 / 24.0 + x2 * (-1.0 / 720.0 + x2 * (1.0 / 40320.0))));
            double nre = cph * are + sph * aim;            // exp(-iEw) = c - i s
            double nim = cph * aim - sph * are;
            double v = nre * nre + nim * nim;
            double s = v;
            s += __shfl_xor(s, 1); s += __shfl_xor(s, 2); s += __shfl_xor(s, 4);
            s += __shfl_xor(s, 8); s += __shfl_xor(s, 16);
            double sc = 1.0 / sqrt(s);
            double nr = nre * sc, ni = nim * sc;
            phre[ii] = nr; phim[ii] = ni;
            phi2l[ii] = (float)(nr * nr + ni * ni);
        } else if (t < NSTEPS && tid >= 256 && tid < 384) {
            const int r = tid - 256;
            const int i = r & 31;
            const int j = j0 + (r >> 5);
            const int curS = 1 - cur;
            const float4* ri = (const float4*)(&CpN[curS][i][0]);
            const float4* rj = (const float4*)(&CpN[cur][j][0]);
            float svq = 0.f;
            #pragma unroll
            for (int m4 = 0; m4 < 8; ++m4) {
                float4 av = ri[m4], bv = rj[m4];
                svq += av.x * bv.x;
                svq += av.y * bv.y;
                svq += av.z * bv.z;
                svq += av.w * bv.w;
            }
            float v2 = svq * svq;
            int bi = i;
            #pragma unroll
            for (int off = 16; off > 0; off >>= 1) {
                float ov = __shfl_xor(v2, off);
                int   oi = __shfl_xor(bi, off);
                if (ov > v2 || (ov == v2 && oi < bi)) { v2 = ov; bi = oi; }
            }
            if (i == 0) kkL[curS][j] = bi;
            const float DE = (i == bi) ? 0.f : (EL[curS][i] - EL[cur][j]);
            featS[r].x = DE;
            featS[r].w = __expf(DE / kbt);
        }
        __syncthreads();

        // ---- ploc (every NSI steps, 4 rows per sibling) + ratio finalize ----
        if ((t % NSI) == 0 && tid < 64) {
            const int ii = iblk * 4 + (tid >> 4), l = tid & 15;
            double are = 0.0, aim = 0.0;
            #pragma unroll
            for (int jj = l; jj < NN; jj += 16) {
                double cij = (double)CpN[cur][jj][ii];   // C_t[i][j] = CT_t[j][i]
                are += cij * phre[jj]; aim += cij * phim[jj];
            }
            are += __shfl_xor(are, 1); aim += __shfl_xor(aim, 1);
            are += __shfl_xor(are, 2); aim += __shfl_xor(aim, 2);
            are += __shfl_xor(are, 4); aim += __shfl_xor(aim, 4);
            are += __shfl_xor(are, 8); aim += __shfl_xor(aim, 8);
            if (l == 0)
                out[((size_t)b * 61 + t / NSI) * NN + ii] = (float)(are * are + aim * aim);
        }
        if (t < NSTEPS && tid < 128) {     // ratio for t+1 (needs fresh phi2l)
            const int i = tid & 31, j = j0 + (tid >> 5);
            const float p_i = phi2l[i], p_j = phi2l[j];
            featS[tid].y = (p_j > 0.01f * p_i) ? (p_i / p_j) : 100.f;
        }
    }
}

// ---------------------------------------------------------------------------
extern "C" void kernel_launch(void* const* d_in, const int* in_sizes, int n_in,
                              void* d_out, int out_size, void* d_ws, size_t ws_size,
                              hipStream_t stream)
{
    const float* Tarr = (const float*)d_in[0];
    const float* ErA  = (const float*)d_in[1];
    const float* ctA  = (const float*)d_in[2];
    const float* dtA  = (const float*)d_in[4];
    const float* psi0 = (const float*)d_in[6];
    const float* Hf   = (const float*)d_in[7];
    const float* W1   = (const float*)d_in[8];
    const float* b1   = (const float*)d_in[9];
    const float* W2   = (const float*)d_in[10];
    const float* b2   = (const float*)d_in[11];
    const float* W3   = (const float*)d_in[12];
    const float* b3   = (const float*)d_in[13];
    const float* W4   = (const float*)d_in[14];
    const float* b4   = (const float*)d_in[15];

    unsigned int* cnt = (unsigned int*)d_ws;                    // 32*600 counters
    float* E_all  = (float*)(cnt + (size_t)NB * NSTEPS);        // 32*601*32
    float* CT_all = E_all + (size_t)NB * NT1 * NN;              // 32*601*32*32
    float* W2p    = CT_all + (size_t)NB * NT1 * NN * NN;        // 7680
    float* W3p    = W2p + 8 * NKB * 48;                         // 7680
    float4* L1W4  = (float4*)(W3p + 8 * NKB * 48);              // 80 f4
    float4* L1B4  = L1W4 + NU;                                  // 80 f4
    float* bpad   = (float*)(L1B4 + NU);                        // 3*80
    double* part_g = (double*)(bpad + 3 * NU);                  // 2*32*512 f64 (256KB)
    float* outp   = (float*)d_out;

    hipMemsetAsync(cnt, 0, (size_t)NB * NSTEPS * sizeof(unsigned int), stream);
    eigh_kernel<<<NB * NT1, 128, 0, stream>>>(Hf, E_all, CT_all);
    wtrans_kernel<<<1, 256, 0, stream>>>(W1, b1, W2, W3, b2, b3, W4,
                                         W2p, W3p, L1W4, L1B4, bpad);

    // dyn LDS: two f4 tables (80 each) + 4x80 biases + hbuf 80*128
    const size_t dynf = (size_t)(8 * NU) + 4 * NU + NU * 128;
    persist_kernel<<<NB * NIB, 1024, dynf * sizeof(float), stream>>>(E_all, CT_all,
        psi0, Tarr, ErA, ctA, dtA, W2p, W3p, L1W4, L1B4, bpad, b4,
        part_g, cnt, outp);
}

// Round 15
// 12389.646 us; speedup vs baseline: 8.3153x; 8.1662x over previous
//
#include <hip/hip_runtime.h>
#include <math.h>

// R15 = resubmission of R11/R14 (verified 12.42ms in R11; R14 bench was an
// infra failure - "container failed twice", no pytest verdict - on source
// byte-equivalent to the R11 kernel that passed).

#define NB 32
#define NN 32
#define NSTEPS 600
#define NT1 601
#define NSI 10
#define NH 75
#define NU 80      // padded u
#define NKB 20     // padded k-blocks of 4 (k padded 75 -> 80)
#define NIB 8      // sibling blocks per batch element (grid = 256 = #CUs)
#define NG 16      // u-groups (16 waves x 5u)

#define ICM2IFS 2.99792458e-05
#define KBOLTZ 0.6950389f
#define TWO_PI 6.283185307179586476925286766559

__device__ __forceinline__ float elu1(float x) { return x > 0.f ? x : (__expf(x) - 1.f); }

// ---------------------------------------------------------------------------
// Phase A: batched 32x32 symmetric eigensolver (parallel cyclic Jacobi).
// R9-proven version: 128 threads (2 waves) per matrix, LDS-distributed
// rotations, tol2 = 1e-16*||A||^2 (V is f32-accumulated).
// ---------------------------------------------------------------------------
__global__ __launch_bounds__(128) void eigh_kernel(const float* __restrict__ Hf,
                                                   float* __restrict__ E_all,
                                                   float* __restrict__ CT_all)
{
    __shared__ double A[NN][NN + 1];
    __shared__ float  V[NN][NN + 1];
    __shared__ double csC[16], csS[16];
    __shared__ int   prC[16], qrC[16];
    __shared__ double redv;
    __shared__ int   rankl[NN];

    const int idx = blockIdx.x;      // b*601 + t
    const int tid = threadIdx.x;
    const float* Hp = Hf + (size_t)idx * (NN * NN);

    for (int e = tid; e < NN * NN; e += 128) {
        A[e >> 5][e & 31] = (double)Hp[e];
        V[e >> 5][e & 31] = ((e >> 5) == (e & 31)) ? 1.f : 0.f;
    }
    __syncthreads();

    if (tid < 64) {                 // original 64-lane mapping -> identical tol2
        double part = 0.0;
        for (int e = tid; e < NN * NN; e += 64) { double v = A[e >> 5][e & 31]; part += v * v; }
        #pragma unroll
        for (int off = 32; off > 0; off >>= 1) part += __shfl_down(part, off);
        if (tid == 0) redv = part;
    }
    __syncthreads();
    const double tol2 = 1e-16 * redv;

    for (int sweep = 0; sweep < 10; ++sweep) {
        for (int r = 0; r < NN - 1; ++r) {
            if (tid < 16) {
                int m = tid, p, q;
                if (m == 0) { p = 0; q = 1 + (r % 31); }
                else { p = 1 + ((m + r) % 31); q = 1 + ((31 - m + r) % 31); }
                double apq = A[p][q];
                double c = 1.0, sn = 0.0;
                if (apq != 0.0) {
                    double theta = 0.5 * (A[q][q] - A[p][p]) / apq;
                    double tt = 1.0 / (fabs(theta) + sqrt(theta * theta + 1.0));
                    if (theta < 0.0) tt = -tt;
                    c = 1.0 / sqrt(tt * tt + 1.0);
                    sn = tt * c;
                }
                csC[m] = c; csS[m] = sn; prC[m] = p; qrC[m] = q;
            }
            __syncthreads();
            #pragma unroll
            for (int it = 0; it < 4; ++it) {          // rows: A <- J^T A (512 tasks)
                int task = tid + it * 128;
                int m = task >> 5, jc = task & 31;
                int p = prC[m], q = qrC[m];
                double c = csC[m], sn = csS[m];
                double ap = A[p][jc], aq = A[q][jc];
                A[p][jc] = c * ap - sn * aq;
                A[q][jc] = sn * ap + c * aq;
            }
            __syncthreads();
            #pragma unroll
            for (int it = 0; it < 8; ++it) {          // cols: A (f64) + V (f32), 1024 tasks
                int task = tid + it * 128;
                int m = (task >> 5) & 15, ir = task & 31;
                int p = prC[m], q = qrC[m];
                if (task < 512) {
                    double c = csC[m], sn = csS[m];
                    double aip = A[ir][p], aiq = A[ir][q];
                    A[ir][p] = c * aip - sn * aiq;
                    A[ir][q] = sn * aip + c * aiq;
                } else {
                    float cf = (float)csC[m], sf = (float)csS[m];
                    float vip = V[ir][p], viq = V[ir][q];
                    V[ir][p] = cf * vip - sf * viq;
                    V[ir][q] = sf * vip + cf * viq;
                }
            }
            __syncthreads();
        }
        if (sweep >= 3) {
            if (tid < 64) {         // original 64-lane mapping -> identical redv
                double o = 0.0;
                for (int e = tid; e < NN * NN; e += 64) {
                    int i2 = e >> 5, j2 = e & 31;
                    double v = A[i2][j2];
                    o += (i2 != j2) ? v * v : 0.0;
                }
                #pragma unroll
                for (int off = 32; off > 0; off >>= 1) o += __shfl_down(o, off);
                if (tid == 0) redv = o;
            }
            __syncthreads();
            if (redv <= tol2) break;
        }
    }
    __syncthreads();

    if (tid < NN) {
        double ei = A[tid][tid];
        int rk = 0;
        for (int j2 = 0; j2 < NN; ++j2) {
            double ej = A[j2][j2];
            rk += (ej < ei || (ej == ei && j2 < tid)) ? 1 : 0;
        }
        rankl[tid] = rk;
        E_all[(size_t)idx * NN + rk] = (float)ei;
    }
    __syncthreads();
    float* ct = CT_all + (size_t)idx * NN * NN;
    for (int e = tid; e < NN * NN; e += 128) {
        int col = e >> 5, m2 = e & 31;
        ct[(size_t)rankl[col] * NN + m2] = V[m2][col];
    }
}

// ---------------------------------------------------------------------------
// Pack weights for 16 u-groups x 5u: Wp[ug 16][kb 20][kp 4][8 (5u + 3 pad)].
// ---------------------------------------------------------------------------
__global__ void wtrans_kernel(const float* __restrict__ W1, const float* __restrict__ b1,
                              const float* __restrict__ W2, const float* __restrict__ W3,
                              const float* __restrict__ b2, const float* __restrict__ b3,
                              const float* __restrict__ W4,
                              float* __restrict__ W2p, float* __restrict__ W3p,
                              float4* __restrict__ L1W4, float4* __restrict__ L1B4,
                              float* __restrict__ bpad)
{
    const int tid = threadIdx.x;
    const int tot = NG * NKB * 4 * 8;          // 10240
    for (int e = tid; e < tot; e += 256) {
        int ug = e / (NKB * 4 * 8);
        int kb = (e / (4 * 8)) % NKB;
        int kp = (e / 8) & 3;
        int uu = e & 7;
        int u = ug * 5 + uu;
        int k = kb * 4 + kp;
        float v2 = 0.f, v3 = 0.f;
        if (uu < 5 && u < NH && k < NH) {
            v2 = W2[u * NH + k];
            v3 = W3[u * NH + k];
        }
        W2p[e] = v2; W3p[e] = v3;
    }
    if (tid < NU) {
        if (tid < NH) {
            const float* w = W1 + tid * 8;
            L1W4[tid] = make_float4(w[0], w[1], w[2], w[7]);
            L1B4[tid] = make_float4(w[3], w[4], w[5], b1[tid]);
            bpad[tid]          = b2[tid];
            bpad[NU + tid]     = b3[tid];
            bpad[2 * NU + tid] = W4[tid];
        } else {
            L1W4[tid] = make_float4(0.f, 0.f, 0.f, 0.f);
            L1B4[tid] = make_float4(0.f, 0.f, 0.f, 0.f);
            bpad[tid] = 0.f; bpad[NU + tid] = 0.f; bpad[2 * NU + tid] = 0.f;
        }
    }
}

// ---------------------------------------------------------------------------
// Phase B persistent kernel. R11-proven: 1024 thr, 16 waves (5u x 2r tile,
// fits the 64-VGPR cap), partial-sum exchange, 512-thr gather, wave-0 norm,
// bit-exact in-kernel kk (sequential float4-row Sv in the norm epoch).
// ---------------------------------------------------------------------------
__global__ __launch_bounds__(1024) void persist_kernel(
    const float* __restrict__ E_all, const float* __restrict__ CT_all,
    const float* __restrict__ psi0,
    const float* __restrict__ Tarr, const float* __restrict__ ErA,
    const float* __restrict__ ctA, const float* __restrict__ dtA,
    const float* __restrict__ W2p, const float* __restrict__ W3p,
    const float4* __restrict__ L1W4g, const float4* __restrict__ L1B4g,
    const float* __restrict__ bpad, const float* __restrict__ b4v,
    double* __restrict__ part_g, unsigned int* __restrict__ cnt,
    float* __restrict__ out)
{
    extern __shared__ __align__(16) float dyn[];
    float4* L1Wl = (float4*)dyn;                // 80 f4
    float4* L1Bl = L1Wl + NU;                   // 80 f4
    float* cst  = (float*)(L1Bl + NU);          // 80
    float* b2l  = cst + NU;                     // 80
    float* b3l  = b2l + NU;                     // 80
    float* W4l  = b3l + NU;                     // 80
    float* hbuf = W4l + NU;                     // 80*128 = 10240 floats

    __shared__ __align__(16) float CpN[2][NN][NN + 4];
    __shared__ float4 featS[128];               // {DE, ratio, Sv, ex} per cell
    __shared__ float2 a4b2[NG][64];
    __shared__ float EL[2][NN];
    __shared__ int   kkL[2][NN];
    __shared__ double phre[NN], phim[NN];
    __shared__ double ppre[4][NN], ppim[4][NN]; // per-column products
    __shared__ double sre[NN], sim[NN];         // sib-summed partials
    __shared__ float phi2l[NN];

    const int tid  = threadIdx.x;
    const int b    = blockIdx.x >> 3;           // sibling sets consecutive
    const int iblk = blockIdx.x & 7;
    const int j0   = iblk * 4;                  // owns columns j0..j0+3
    const int ug   = __builtin_amdgcn_readfirstlane(tid >> 6);  // uniform wave id 0..15
    const int rg   = tid & 63;                  // handles cells 2*rg, 2*rg+1
    const int U    = ug * 5;

    const float kbt = KBOLTZ * Tarr[b];
    const float er  = ErA[b];
    const float cti = ctA[b];
    const double dtb = (double)dtA[b];
    const float b4s = b4v[0];

    const float4* W2g = (const float4*)(W2p + (size_t)ug * (NKB * 32));
    const float4* W3g = (const float4*)(W3p + (size_t)ug * (NKB * 32));

    // ---- stage small loop-invariant tables into LDS (once) ----
    if (tid < NU) {
        L1Wl[tid] = L1W4g[tid];
        L1Bl[tid] = L1B4g[tid];
        b2l[tid] = bpad[tid];
        b3l[tid] = bpad[NU + tid];
        W4l[tid] = bpad[2 * NU + tid];
    }
    __syncthreads();
    if (tid < NU) {     // per-b constant part of layer-1 preactivation
        float4 lb = L1Bl[tid];
        cst[tid] = lb.w + lb.x * kbt + lb.y * er + lb.z * cti;
    }

    // ---- prime: C_0, C_1, E[0], E[1]; init phiB; featS + kk for s=1 ----
    {
        const float* c0g = CT_all + (size_t)b * NT1 * NN * NN;
        const float* c1g = c0g + NN * NN;
        for (int e = tid; e < NN * NN; e += 1024) {
            CpN[0][e >> 5][e & 31] = c0g[e];
            CpN[1][e >> 5][e & 31] = c1g[e];
        }
        if (tid < NN) {
            EL[0][tid] = E_all[((size_t)b * NT1 + 0) * NN + tid];
            EL[1][tid] = E_all[((size_t)b * NT1 + 1) * NN + tid];
        }
        __syncthreads();
        if (tid < NN) {
            const int i = tid;
            double acc = 0.0;
            for (int j = 0; j < NN; ++j) acc += (double)CpN[0][i][j] * (double)psi0[b * NN + j];
            phre[i] = acc; phim[i] = 0.0;
            phi2l[i] = (float)(acc * acc);
            if (iblk == 0) {
                float p0 = psi0[b * NN + i];
                out[((size_t)b * 61) * NN + i] = p0 * p0;
            }
        }
        __syncthreads();
        {   // strided Sv for step-1 features (8 lanes per cell, as in R9)
            const int r = tid >> 3, c = tid & 7;
            const int i = r & 31, j = j0 + (r >> 5);
            float Sv = 0.f;
            #pragma unroll
            for (int m = c; m < NN; m += 8)
                Sv += CpN[1][i][m] * CpN[0][j][m];
            Sv += __shfl_xor(Sv, 1); Sv += __shfl_xor(Sv, 2); Sv += __shfl_xor(Sv, 4);
            if (c == 0) featS[r] = make_float4(0.f, 0.f, Sv, 0.f);
        }
        __syncthreads();
        if (tid < 128) {    // SEQUENTIAL Sv (float4 rows) -> kk, DE, ratio, ex
            const int r = tid, i = r & 31;
            const int j = j0 + (r >> 5);
            const float4* ri = (const float4*)(&CpN[1][i][0]);
            const float4* rj = (const float4*)(&CpN[0][j][0]);
            float svq = 0.f;
            #pragma unroll
            for (int m4 = 0; m4 < 8; ++m4) {
                float4 av = ri[m4], bv = rj[m4];
                svq += av.x * bv.x;
                svq += av.y * bv.y;
                svq += av.z * bv.z;
                svq += av.w * bv.w;
            }
            float v2 = svq * svq;
            int bi = i;
            #pragma unroll
            for (int off = 16; off > 0; off >>= 1) {
                float ov = __shfl_xor(v2, off);
                int   oi = __shfl_xor(bi, off);
                if (ov > v2 || (ov == v2 && oi < bi)) { v2 = ov; bi = oi; }
            }
            if (i == 0) kkL[1][j] = bi;
            const float DE = (i == bi) ? 0.f : (EL[1][i] - EL[0][j]);
            const float Sv = featS[r].z;
            const float p_i = phi2l[i], p_j = phi2l[j];
            const float ratio = (p_j > 0.01f * p_i) ? (p_i / p_j) : 100.f;
            featS[r] = make_float4(DE, ratio, Sv, __expf(DE / kbt));
        }
    }

    for (int t = 1; t <= NSTEPS; ++t) {
        __syncthreads();                        // featS / phi2l visible
        const int cur = t & 1;

        // ---- issue prefetch loads for step t+1 (retire during MLP) ----
        float2 cpre = make_float2(0.f, 0.f);
        float  epre = 0.f;
        if (t < NSTEPS) {
            if (tid < 512) {
                const float* c1g = CT_all + ((size_t)b * NT1 + t + 1) * (NN * NN);
                cpre = ((const float2*)c1g)[tid];
            }
            if (tid < NN) epre = E_all[((size_t)b * NT1 + t + 1) * NN + tid];
        }

        // ---- layer 1 (features -> h1), tile 5u x 2r ----
        {
            float4 f0 = featS[2 * rg], f1 = featS[2 * rg + 1];
            #pragma unroll
            for (int u = 0; u < 5; ++u) {
                float4 wv = L1Wl[U + u];
                float c = cst[U + u];
                float2 hv;
                hv.x = elu1(c + wv.x * f0.x + wv.y * f0.y + wv.z * f0.z + wv.w * f0.w);
                hv.y = elu1(c + wv.x * f1.x + wv.y * f1.y + wv.z * f1.z + wv.w * f1.w);
                *(float2*)(hbuf + (U + u) * 128 + 2 * rg) = hv;
            }
        }
        __syncthreads();

        // ---- layer 2 (h1 -> h2): weights via wave-uniform scalar loads ----
        float2 acc[5];
        #pragma unroll
        for (int u = 0; u < 5; ++u) { float bb = b2l[U + u]; acc[u] = make_float2(bb, bb); }
        for (int kb = 0; kb < NKB; ++kb) {
            float4 wv[8];
            float2 hv[4];
            #pragma unroll
            for (int m = 0; m < 8; ++m) wv[m] = W2g[kb * 8 + m];     // uniform -> s_load
            #pragma unroll
            for (int kk = 0; kk < 4; ++kk)
                hv[kk] = *(const float2*)(hbuf + (kb * 4 + kk) * 128 + 2 * rg);
            #pragma unroll
            for (int kk = 0; kk < 4; ++kk) {
                const float* wf = (const float*)&wv[kk * 2];
                #pragma unroll
                for (int u = 0; u < 5; ++u) {
                    float wS = wf[u];
                    acc[u].x += wS * hv[kk].x; acc[u].y += wS * hv[kk].y;
                }
            }
        }
        __syncthreads();    // all reads of h1 done before overwriting hbuf
        #pragma unroll
        for (int u = 0; u < 5; ++u) {
            float2 hv; hv.x = elu1(acc[u].x); hv.y = elu1(acc[u].y);
            *(float2*)(hbuf + (U + u) * 128 + 2 * rg) = hv;
        }
        __syncthreads();

        // ---- layer 3 (h2 -> h3 in registers) ----
        #pragma unroll
        for (int u = 0; u < 5; ++u) { float bb = b3l[U + u]; acc[u] = make_float2(bb, bb); }
        for (int kb = 0; kb < NKB; ++kb) {
            float4 wv[8];
            float2 hv[4];
            #pragma unroll
            for (int m = 0; m < 8; ++m) wv[m] = W3g[kb * 8 + m];     // uniform -> s_load
            #pragma unroll
            for (int kk = 0; kk < 4; ++kk)
                hv[kk] = *(const float2*)(hbuf + (kb * 4 + kk) * 128 + 2 * rg);
            #pragma unroll
            for (int kk = 0; kk < 4; ++kk) {
                const float* wf = (const float*)&wv[kk * 2];
                #pragma unroll
                for (int u = 0; u < 5; ++u) {
                    float wS = wf[u];
                    acc[u].x += wS * hv[kk].x; acc[u].y += wS * hv[kk].y;
                }
            }
        }
        // ---- layer 4 partials ----
        {
            float2 p4 = make_float2(0.f, 0.f);
            #pragma unroll
            for (int u = 0; u < 5; ++u) {
                float w4 = W4l[U + u];
                p4.x += w4 * elu1(acc[u].x); p4.y += w4 * elu1(acc[u].y);
            }
            a4b2[ug][rg] = p4;
        }
        __syncthreads();

        // ---- finalize corr, IN-REGISTER column correction, per-column
        //      complex products into LDS (pre-barrier partial reduction) ----
        if (tid < 128) {
            const int r = tid;
            const int i = r & 31;
            const int jj = r >> 5;              // 0..3
            const int j = j0 + jj;
            float a4 = b4s;
            #pragma unroll
            for (int g = 0; g < NG; ++g) {
                float2 pv = a4b2[g][r >> 1];
                a4 += (r & 1) ? pv.y : pv.x;
            }
            const float corr = elu1(a4) + 1.f;
            float s2v = featS[r].z * corr;
            const int kj = kkL[cur][j];
            double v = (double)s2v;
            double cd = (i == kj) ? 0.0 : v * v;        // reduce over i (32 lanes)
            cd += __shfl_xor(cd, 1);  cd += __shfl_xor(cd, 2);
            cd += __shfl_xor(cd, 4);  cd += __shfl_xor(cd, 8);
            cd += __shfl_xor(cd, 16);
            if (i == kj) {
                double nrm = fabs(v); nrm = (nrm > 0.0) ? nrm : 1.0;
                double rem = 1.0 - cd;
                v = (rem > 0.0) ? (sqrt(rem) * v / nrm) : v;
                v = (double)(float)v;           // keep f32 rounding as before
            }
            ppre[jj][i] = v * phre[j];
            ppim[jj][i] = v * phim[j];
        }

        // ---- commit prefetch into dead ping-pong slots ----
        if (t < NSTEPS) {
            if (tid < 512) {
                const int e0 = tid * 2;
                CpN[1 - cur][e0 >> 5][e0 & 31] = cpre.x;
                CpN[1 - cur][e0 >> 5][(e0 & 31) + 1] = cpre.y;
            }
            if (tid < NN) EL[1 - cur][tid] = epre;
        }
        __syncthreads();

        // ---- sum own 4 columns, coherent-store partials, signal (wave 0) ----
        if (tid < 32) {
            const int i = tid;
            double pr = ((ppre[0][i] + ppre[1][i]) + ppre[2][i]) + ppre[3][i];
            double pi = ((ppim[0][i] + ppim[1][i]) + ppim[2][i]) + ppim[3][i];
            double* pg = part_g + ((size_t)cur * NB + b) * 512;
            __hip_atomic_store(&pg[i * 8 + iblk], pr,
                               __ATOMIC_RELAXED, __HIP_MEMORY_SCOPE_AGENT);
            __hip_atomic_store(&pg[256 + i * 8 + iblk], pi,
                               __ATOMIC_RELAXED, __HIP_MEMORY_SCOPE_AGENT);
            asm volatile("s_waitcnt vmcnt(0)" ::: "memory");    // drain (wave 0)
            if (tid == 0)
                __hip_atomic_fetch_add(cnt + (size_t)b * NSTEPS + (t - 1), 1u,
                                       __ATOMIC_RELAXED, __HIP_MEMORY_SCOPE_AGENT);
        }

        // ---- strided Sv for t+1 features — hidden inside the spin window ----
        if (t < NSTEPS) {
            const int curS = 1 - cur;
            const int r = tid >> 3, c = tid & 7;
            const int i = r & 31, j = j0 + (r >> 5);
            float Sv = 0.f;
            #pragma unroll
            for (int m = c; m < NN; m += 8)
                Sv += CpN[curS][i][m] * CpN[1 - curS][j][m];
            Sv += __shfl_xor(Sv, 1); Sv += __shfl_xor(Sv, 2); Sv += __shfl_xor(Sv, 4);
            if (c == 0) featS[r] = make_float4(0.f, 0.f, Sv, 0.f);
        }

        // ---- sibling barrier: wait for 8 arrivals ----
        if (tid == 0) {
            const unsigned int* c = cnt + (size_t)b * NSTEPS + (t - 1);
            while (__hip_atomic_load(c, __ATOMIC_RELAXED, __HIP_MEMORY_SCOPE_AGENT)
                   < (unsigned)NIB) {
                __builtin_amdgcn_s_sleep(2);    // ~128cyc between polls
            }
        }
        __syncthreads();

        // ---- gather partials: tid = comp*256 + i*8 + sib; 3-level sib-sum ----
        if (tid < 512) {
            const double* pg = part_g + ((size_t)cur * NB + b) * 512;
            double v = __hip_atomic_load(&pg[tid], __ATOMIC_RELAXED,
                                         __HIP_MEMORY_SCOPE_AGENT);
            v += __shfl_xor(v, 1); v += __shfl_xor(v, 2); v += __shfl_xor(v, 4);
            if ((tid & 7) == 0) {
                const int i = (tid >> 3) & 31;
                if (tid < 256) sre[i] = v; else sim[i] = v;
            }
        }
        __syncthreads();

        // ---- fused phase + normalize (wave 0) || kk for t+1 (waves 4-5,
        //      SEQUENTIAL float4-row Sv -> bit-exact) ----
        if (tid < NN) {
            const int ii = tid;
            double are = sre[ii], aim = sim[ii];
            double th = (double)EL[cur][ii] * (TWO_PI * ICM2IFS) * dtb;   // |th| < ~0.1
            double x2 = th * th;        // poly sincos, |err| ~1e-16 at this range
            double sph = th * (1.0 + x2 * (-1.0 / 6.0 + x2 * (1.0 / 120.0 + x2 * (-1.0 / 5040.0 + x2 * (1.0 / 362880.0)))));
            double cph = 1.0 + x2 * (-0.5 + x2 * (1.0 / 24.0 + x2 * (-1.0 / 720.0 + x2 * (1.0 / 40320.0))));
            double nre = cph * are + sph * aim;            // exp(-iEw) = c - i s
            double nim = cph * aim - sph * are;
            double v = nre * nre + nim * nim;
            double s = v;
            s += __shfl_xor(s, 1); s += __shfl_xor(s, 2); s += __shfl_xor(s, 4);
            s += __shfl_xor(s, 8); s += __shfl_xor(s, 16);
            double sc = 1.0 / sqrt(s);
            double nr = nre * sc, ni = nim * sc;
            phre[ii] = nr; phim[ii] = ni;
            phi2l[ii] = (float)(nr * nr + ni * ni);
        } else if (t < NSTEPS && tid >= 256 && tid < 384) {
            const int r = tid - 256;
            const int i = r & 31;
            const int j = j0 + (r >> 5);
            const int curS = 1 - cur;
            const float4* ri = (const float4*)(&CpN[curS][i][0]);
            const float4* rj = (const float4*)(&CpN[cur][j][0]);
            float svq = 0.f;
            #pragma unroll
            for (int m4 = 0; m4 < 8; ++m4) {
                float4 av = ri[m4], bv = rj[m4];
                svq += av.x * bv.x;
                svq += av.y * bv.y;
                svq += av.z * bv.z;
                svq += av.w * bv.w;
            }
            float v2 = svq * svq;
            int bi = i;
            #pragma unroll
            for (int off = 16; off > 0; off >>= 1) {
                float ov = __shfl_xor(v2, off);
                int   oi = __shfl_xor(bi, off);
                if (ov > v2 || (ov == v2 && oi < bi)) { v2 = ov; bi = oi; }
            }
            if (i == 0) kkL[curS][j] = bi;
            const float DE = (i == bi) ? 0.f : (EL[curS][i] - EL[cur][j]);
            featS[r].x = DE;
            featS[r].w = __expf(DE / kbt);
        }
        __syncthreads();

        // ---- ploc (every NSI steps, 4 rows per sibling) + ratio finalize ----
        if ((t % NSI) == 0 && tid < 64) {
            const int ii = iblk * 4 + (tid >> 4), l = tid & 15;
            double are = 0.0, aim = 0.0;
            #pragma unroll
            for (int jj = l; jj < NN; jj += 16) {
                double cij = (double)CpN[cur][jj][ii];   // C_t[i][j] = CT_t[j][i]
                are += cij * phre[jj]; aim += cij * phim[jj];
            }
            are += __shfl_xor(are, 1); aim += __shfl_xor(aim, 1);
            are += __shfl_xor(are, 2); aim += __shfl_xor(aim, 2);
            are += __shfl_xor(are, 4); aim += __shfl_xor(aim, 4);
            are += __shfl_xor(are, 8); aim += __shfl_xor(aim, 8);
            if (l == 0)
                out[((size_t)b * 61 + t / NSI) * NN + ii] = (float)(are * are + aim * aim);
        }
        if (t < NSTEPS && tid < 128) {     // ratio for t+1 (needs fresh phi2l)
            const int i = tid & 31, j = j0 + (tid >> 5);
            const float p_i = phi2l[i], p_j = phi2l[j];
            featS[tid].y = (p_j > 0.01f * p_i) ? (p_i / p_j) : 100.f;
        }
    }
}

// ---------------------------------------------------------------------------
extern "C" void kernel_launch(void* const* d_in, const int* in_sizes, int n_in,
                              void* d_out, int out_size, void* d_ws, size_t ws_size,
                              hipStream_t stream)
{
    const float* Tarr = (const float*)d_in[0];
    const float* ErA  = (const float*)d_in[1];
    const float* ctA  = (const float*)d_in[2];
    const float* dtA  = (const float*)d_in[4];
    const float* psi0 = (const float*)d_in[6];
    const float* Hf   = (const float*)d_in[7];
    const float* W1   = (const float*)d_in[8];
    const float* b1   = (const float*)d_in[9];
    const float* W2   = (const float*)d_in[10];
    const float* b2   = (const float*)d_in[11];
    const float* W3   = (const float*)d_in[12];
    const float* b3   = (const float*)d_in[13];
    const float* W4   = (const float*)d_in[14];
    const float* b4   = (const float*)d_in[15];

    unsigned int* cnt = (unsigned int*)d_ws;                    // 32*600 counters
    float* E_all  = (float*)(cnt + (size_t)NB * NSTEPS);        // 32*601*32
    float* CT_all = E_all + (size_t)NB * NT1 * NN;              // 32*601*32*32
    float* W2p    = CT_all + (size_t)NB * NT1 * NN * NN;        // 10240
    float* W3p    = W2p + NG * NKB * 32;                        // 10240
    float4* L1W4  = (float4*)(W3p + NG * NKB * 32);             // 80 f4
    float4* L1B4  = L1W4 + NU;                                  // 80 f4
    float* bpad   = (float*)(L1B4 + NU);                        // 3*80
    double* part_g = (double*)(bpad + 3 * NU);                  // 2*32*512 f64 (256KB)
    float* outp   = (float*)d_out;

    hipMemsetAsync(cnt, 0, (size_t)NB * NSTEPS * sizeof(unsigned int), stream);
    eigh_kernel<<<NB * NT1, 128, 0, stream>>>(Hf, E_all, CT_all);
    wtrans_kernel<<<1, 256, 0, stream>>>(W1, b1, W2, W3, b2, b3, W4,
                                         W2p, W3p, L1W4, L1B4, bpad);

    // dyn LDS: two f4 tables (80 each) + 4x80 biases + hbuf 80*128
    const size_t dynf = (size_t)(8 * NU) + 4 * NU + NU * 128;
    persist_kernel<<<NB * NIB, 1024, dynf * sizeof(float), stream>>>(E_all, CT_all,
        psi0, Tarr, ErA, ctA, dtA, W2p, W3p, L1W4, L1B4, bpad, b4,
        part_g, cnt, outp);
}